// Round 3
// baseline (515.962 us; speedup 1.0000x reference)
//
#include <hip/hip_runtime.h>
#include <hip/hip_bf16.h>
#include <cstdint>
#include <cstdio>

typedef unsigned short u16;
typedef unsigned int   u32;
typedef __attribute__((ext_vector_type(8))) short bf16x8;   // 8 bf16 (4 VGPRs)
typedef __attribute__((ext_vector_type(4))) float f32x4;
typedef __attribute__((ext_vector_type(4))) u16   u16x4;

#define GLOBAL_AS __attribute__((address_space(1)))
#define LDS_AS    __attribute__((address_space(3)))

static __device__ __forceinline__ u16 f2bf(float f) {
  u32 u = __builtin_bit_cast(u32, f);
  u = (u + 0x7fffu + ((u >> 16) & 1u)) >> 16;   // RNE
  return (u16)u;
}
static __device__ __forceinline__ float bf2f(u16 v) {
  return __builtin_bit_cast(float, (u32)v << 16);
}
static __device__ __forceinline__ void gload_lds16(const void* g, void* l) {
  __builtin_amdgcn_global_load_lds((GLOBAL_AS u32*)g, (LDS_AS u32*)l, 16, 0, 0);
}

// ---------------------------------------------------------------------------
__global__ void k_cvt(const float* __restrict__ src, int ld, int c0,
                      int rows_src, int cols4, int total4,
                      u16* __restrict__ dst, int ldd, int dcol) {
  int gid = blockIdx.x * 256 + threadIdx.x;
  if (gid >= total4) return;
  int r = gid / cols4;
  int c = (gid - r * cols4) * 4;
  u16x4 o = {0, 0, 0, 0};
  if (r < rows_src) {
    const float4 v = *(const float4*)&src[(size_t)r * ld + c0 + c];
    o[0] = f2bf(v.x); o[1] = f2bf(v.y); o[2] = f2bf(v.z); o[3] = f2bf(v.w);
  }
  *(u16x4*)&dst[(size_t)r * ldd + dcol + c] = o;
}

// ---------------------------------------------------------------------------
__global__ void k_init(const float* __restrict__ rough,
                       const float* __restrict__ bout,
                       float* __restrict__ out) {
  int i = blockIdx.x * 256 + threadIdx.x;
  if (i >= 1024 * 65) return;
  int bi = i / 65, c = i - bi * 65;
  out[i] = (c == 0) ? 1e-7f : rough[bi * 64 + c - 1] + bout[0];
}

// ---------------------------------------------------------------------------
__global__ void k_build_cmat(const float* __restrict__ ments,
                             const float* __restrict__ allm,
                             const float* __restrict__ pw,
                             const int* __restrict__ topidx,
                             u16* __restrict__ Cmat, int r0) {
  int gid = blockIdx.x * 256 + threadIdx.x;   // 16384*272 exact
  int lr = gid / 272;
  int c4 = gid - lr * 272;
  int r  = r0 + lr;
  int bi = r >> 6;
  u16x4 o;
  if (c4 < 256) {
    int k   = c4 * 4;
    int idx = topidx[r];
    float4 a = *(const float4*)&ments[(size_t)bi * 1024 + k];
    float4 b = *(const float4*)&allm[(size_t)idx * 1024 + k];
    o[0] = f2bf(a.x * b.x); o[1] = f2bf(a.y * b.y);
    o[2] = f2bf(a.z * b.z); o[3] = f2bf(a.w * b.w);
  } else {
    int k = (c4 - 256) * 4;
    float4 p = *(const float4*)&pw[(size_t)r * 64 + k];
    o[0] = f2bf(p.x); o[1] = f2bf(p.y); o[2] = f2bf(p.z); o[3] = f2bf(p.w);
  }
  *(u16x4*)&Cmat[(size_t)lr * 1088 + c4 * 4] = o;
}

// ---------------------------------------------------------------------------
// gemm128: old 128x128 2-phase kernel, used only for the tiny Aproj GEMM.
__global__ __launch_bounds__(256)
void gemm128(const u16* __restrict__ A, int lda,
             const u16* __restrict__ B, int ldb, int Ksteps,
             u16* __restrict__ C, int ldc) {
  __shared__ u16 As[128 * 64];
  __shared__ u16 Bs[128 * 64];
  const int t = threadIdx.x;
  const int w = t >> 6, l = t & 63;
  const int wr = w >> 1, wc = w & 1;
  const int brow = blockIdx.x * 128;
  const int bcol = blockIdx.y * 128;
  const int srow = t >> 3;
  const int scol = (t & 7) * 8;
  const int gsw  = (((t & 7) ^ ((t >> 3) & 7))) * 8;

  f32x4 acc[4][4] = {};
  for (int ks = 0; ks < Ksteps; ++ks) {
    const int kb = ks * 64;
#pragma unroll
    for (int q = 0; q < 4; ++q) {
      int r = q * 32 + srow;
      gload_lds16(A + (size_t)(brow + r) * lda + kb + gsw, &As[r * 64 + scol]);
      gload_lds16(B + (size_t)(bcol + r) * ldb + kb + gsw, &Bs[r * 64 + scol]);
    }
    __syncthreads();
#pragma unroll
    for (int kk = 0; kk < 2; ++kk) {
      bf16x8 af[4], bfr[4];
      const int pg = ((kk * 4 + (l >> 4)) ^ (l & 7)) * 8;
#pragma unroll
      for (int m = 0; m < 4; ++m)
        af[m] = *(const bf16x8*)&As[(wr * 64 + m * 16 + (l & 15)) * 64 + pg];
#pragma unroll
      for (int n = 0; n < 4; ++n)
        bfr[n] = *(const bf16x8*)&Bs[(wc * 64 + n * 16 + (l & 15)) * 64 + pg];
#pragma unroll
      for (int m = 0; m < 4; ++m)
#pragma unroll
        for (int n = 0; n < 4; ++n)
          acc[m][n] = __builtin_amdgcn_mfma_f32_16x16x32_bf16(af[m], bfr[n], acc[m][n], 0, 0, 0);
    }
    __syncthreads();
  }
#pragma unroll
  for (int m = 0; m < 4; ++m)
#pragma unroll
    for (int n = 0; n < 4; ++n)
#pragma unroll
      for (int reg = 0; reg < 4; ++reg) {
        int row = brow + wr * 64 + m * 16 + (l >> 4) * 4 + reg;
        int col = bcol + wc * 64 + n * 16 + (l & 15);
        C[(size_t)row * ldc + col] = f2bf(acc[m][n][reg]);
      }
}

// ---------------------------------------------------------------------------
// gemm256: 256x256 tile, BK=64, 512 thr (8 waves, 2Mx4N), 8-phase pipelined
// schedule with counted vmcnt (T3+T4), T2 swizzle, T5 setprio.
// LDS 128KiB dynamic: As[2buf][2half][128][64], Bs same.
// A halves row-interleaved (half h holds global rows with (g>>5)&1==h) so
// phase q (m-quarter q) reads only half q&1 -> quarter freed per phase.
// B frags all register-cached in q0 -> B(t) LDS dead after q0.
// Stage schedule (phase P=p*4+q of iter i, tiles t=2i,t+1):
//   P0: Ah1(t+1)  P1: Bh0(t+2)  P2: Bh1(t+2)  P3: Ah0(t+2)
//   P4: Ah1(t+2)  P5: Bh0(t+3)  P6: Bh1(t+3)  P7: Ah0(t+3)
// Every stage targets a region whose last reader finished >=1 barrier ago.
// Waits: vmcnt(8) at P0,P1,P4,P5 (8 loads = 4 half-tiles in flight); last
// iteration of even NT: P4 vmcnt(2), P5 vmcnt(0). Odd NT: drained tail tile.
template<bool FUSED>
__global__ __launch_bounds__(512, 1)
void gemm256(const u16* __restrict__ A, int lda,
             const u16* __restrict__ B, int ldb, int NT,
             u16* __restrict__ C, int ldc,
             const u16* __restrict__ Aproj, const u16* __restrict__ Bproj,
             const float* __restrict__ b1, const float* __restrict__ Wout,
             const int* __restrict__ topidx, float* __restrict__ out, int r0) {
  extern __shared__ u16 lds[];
  u16* As = lds;                        // [2][2][128][64]
  u16* Bs = lds + 2 * 2 * 128 * 64;     // [2][2][128][64]

  const int t = threadIdx.x;
  const int l = t & 63;
  const int w = t >> 6;                 // 0..7
  const int wrow = w >> 2, wcol = w & 3;
  const int brow = blockIdx.x * 256;
  const int bcol = blockIdx.y * 256;

  const int sr  = t >> 3;               // 0..63
  const int sc  = (t & 7) * 8;          // linear LDS dest col
  const int gsw = ((t & 7) ^ (sr & 7)) * 8;  // pre-swizzled global col

  auto stageA = [&](int kt, int h) {
#pragma unroll
    for (int s = 0; s < 2; ++s) {
      int lr = sr + 64 * s;
      int g  = ((lr >> 5) << 6) + h * 32 + (lr & 31);   // interleaved half
      gload_lds16(A + (size_t)(brow + g) * lda + kt * 64 + gsw,
                  &As[(((kt & 1) * 2 + h) * 128 + lr) * 64 + sc]);
    }
  };
  auto stageB = [&](int kt, int h) {
#pragma unroll
    for (int s = 0; s < 2; ++s) {
      int lr = sr + 64 * s;
      gload_lds16(B + (size_t)(bcol + h * 128 + lr) * ldb + kt * 64 + gsw,
                  &Bs[(((kt & 1) * 2 + h) * 128 + lr) * 64 + sc]);
    }
  };

  f32x4 acc[8][4] = {};

  // prologue (steady-state issue order): Bh0(0),Bh1(0),Ah0(0),Ah1(0),Bh0(1),Bh1(1),Ah0(1)
  stageB(0, 0); stageB(0, 1); stageA(0, 0); stageA(0, 1);
  stageB(1, 0); stageB(1, 1); stageA(1, 0);

  const int niters = NT >> 1;
  for (int i = 0; i < niters; ++i) {
    const bool lastp = (2 * i + 2 >= NT);
#pragma unroll
    for (int p = 0; p < 2; ++p) {
      bf16x8 bfr[4][2];                 // B frags, live all 4 phases
#pragma unroll
      for (int q = 0; q < 4; ++q) {
        // --- counted waits ---
        if (p == 0 && q <= 1) {
          asm volatile("s_waitcnt vmcnt(8)" ::: "memory");
        } else if (p == 1 && q == 0) {
          if (lastp) asm volatile("s_waitcnt vmcnt(2)" ::: "memory");
          else       asm volatile("s_waitcnt vmcnt(8)" ::: "memory");
        } else if (p == 1 && q == 1) {
          if (lastp) asm volatile("s_waitcnt vmcnt(0)" ::: "memory");
          else       asm volatile("s_waitcnt vmcnt(8)" ::: "memory");
        }
        __builtin_amdgcn_s_barrier();
        __builtin_amdgcn_sched_barrier(0);

        // --- ds reads ---
        if (q == 0) {
#pragma unroll
          for (int n = 0; n < 4; ++n) {
            int row = wcol * 64 + n * 16 + (l & 15);
            int hb = row >> 7, lrb = row & 127;
#pragma unroll
            for (int kk = 0; kk < 2; ++kk) {
              int gran = (kk * 4 + (l >> 4)) ^ (l & 7);
              bfr[n][kk] = *(const bf16x8*)&Bs[((p * 2 + hb) * 128 + lrb) * 64 + gran * 8];
            }
          }
        }
        bf16x8 af[2][2];
#pragma unroll
        for (int m2 = 0; m2 < 2; ++m2) {
          int m = 2 * q + m2;
          int g = wrow * 128 + m * 16 + (l & 15);
          int lra = ((g >> 6) << 5) + (g & 31);
#pragma unroll
          for (int kk = 0; kk < 2; ++kk) {
            int gran = (kk * 4 + (l >> 4)) ^ (l & 7);
            af[m2][kk] = *(const bf16x8*)&As[((p * 2 + (q & 1)) * 128 + lra) * 64 + gran * 8];
          }
        }

        // --- stage per schedule ---
        if (p == 0) {
          if (q == 0) stageA(2 * i + 1, 1);
          else if (!lastp) {
            if (q == 1)      stageB(2 * i + 2, 0);
            else if (q == 2) stageB(2 * i + 2, 1);
            else             stageA(2 * i + 2, 0);
          }
        } else {
          if (!lastp) {
            if (q == 0) stageA(2 * i + 2, 1);
            else if (2 * i + 3 < NT) {
              if (q == 1)      stageB(2 * i + 3, 0);
              else if (q == 2) stageB(2 * i + 3, 1);
              else             stageA(2 * i + 3, 0);
            }
          }
        }

        // --- MFMA cluster ---
        __builtin_amdgcn_s_setprio(1);
#pragma unroll
        for (int m2 = 0; m2 < 2; ++m2)
#pragma unroll
          for (int n = 0; n < 4; ++n)
#pragma unroll
            for (int kk = 0; kk < 2; ++kk)
              acc[2 * q + m2][n] = __builtin_amdgcn_mfma_f32_16x16x32_bf16(
                  af[m2][kk], bfr[n][kk], acc[2 * q + m2][n], 0, 0, 0);
        __builtin_amdgcn_s_setprio(0);
      }
    }
  }

  // --- drained tail tile (odd NT) ---
  if (NT & 1) {
    const int bufp = (NT - 1) & 1;
    asm volatile("s_waitcnt vmcnt(0)" ::: "memory");
    __builtin_amdgcn_s_barrier();
    __builtin_amdgcn_sched_barrier(0);
    bf16x8 bfr[4][2];
#pragma unroll
    for (int n = 0; n < 4; ++n) {
      int row = wcol * 64 + n * 16 + (l & 15);
      int hb = row >> 7, lrb = row & 127;
#pragma unroll
      for (int kk = 0; kk < 2; ++kk) {
        int gran = (kk * 4 + (l >> 4)) ^ (l & 7);
        bfr[n][kk] = *(const bf16x8*)&Bs[((bufp * 2 + hb) * 128 + lrb) * 64 + gran * 8];
      }
    }
#pragma unroll
    for (int q = 0; q < 4; ++q) {
      bf16x8 af[2][2];
#pragma unroll
      for (int m2 = 0; m2 < 2; ++m2) {
        int m = 2 * q + m2;
        int g = wrow * 128 + m * 16 + (l & 15);
        int lra = ((g >> 6) << 5) + (g & 31);
#pragma unroll
        for (int kk = 0; kk < 2; ++kk) {
          int gran = (kk * 4 + (l >> 4)) ^ (l & 7);
          af[m2][kk] = *(const bf16x8*)&As[((bufp * 2 + (q & 1)) * 128 + lra) * 64 + gran * 8];
        }
      }
      __builtin_amdgcn_s_setprio(1);
#pragma unroll
      for (int m2 = 0; m2 < 2; ++m2)
#pragma unroll
        for (int n = 0; n < 4; ++n)
#pragma unroll
          for (int kk = 0; kk < 2; ++kk)
            acc[2 * q + m2][n] = __builtin_amdgcn_mfma_f32_16x16x32_bf16(
                af[m2][kk], bfr[n][kk], acc[2 * q + m2][n], 0, 0, 0);
      __builtin_amdgcn_s_setprio(0);
    }
  }

  // --- epilogue ---
  if constexpr (FUSED) {
    float b1c[4], wo[4];
#pragma unroll
    for (int n = 0; n < 4; ++n) {
      int col = bcol + wcol * 64 + n * 16 + (l & 15);
      b1c[n] = b1[col];
      wo[n]  = Wout[col];
    }
#pragma unroll
    for (int m = 0; m < 8; ++m) {
#pragma unroll
      for (int reg = 0; reg < 4; ++reg) {
        int gr = r0 + brow + wrow * 128 + m * 16 + (l >> 4) * 4 + reg;
        int bi = gr >> 6;
        int mi = topidx[gr];
        float s = 0.f;
#pragma unroll
        for (int n = 0; n < 4; ++n) {
          int col = bcol + wcol * 64 + n * 16 + (l & 15);
          float v = acc[m][n][reg] + bf2f(Aproj[(size_t)bi * 1024 + col])
                  + bf2f(Bproj[(size_t)mi * 1024 + col]) + b1c[n];
          v = v > 0.f ? v : 0.01f * v;          // leaky_relu(0.01)
          s += v * wo[n];
        }
        s += __shfl_xor(s, 1);
        s += __shfl_xor(s, 2);
        s += __shfl_xor(s, 4);
        s += __shfl_xor(s, 8);
        if ((l & 15) == 0)
          atomicAdd(&out[bi * 65 + 1 + (gr & 63)], s);
      }
    }
  } else {
#pragma unroll
    for (int m = 0; m < 8; ++m)
#pragma unroll
      for (int n = 0; n < 4; ++n)
#pragma unroll
        for (int reg = 0; reg < 4; ++reg) {
          int row = brow + wrow * 128 + m * 16 + (l >> 4) * 4 + reg;
          int col = bcol + wcol * 64 + n * 16 + (l & 15);
          C[(size_t)row * ldc + col] = f2bf(acc[m][n][reg]);
        }
  }
}

// ---------------------------------------------------------------------------
extern "C" void kernel_launch(void* const* d_in, const int* in_sizes, int n_in,
                              void* d_out, int out_size, void* d_ws, size_t ws_size,
                              hipStream_t stream) {
  const float* allm  = (const float*)d_in[0];   // [10000,1024]
  const float* ments = (const float*)d_in[1];   // [1024,1024]
  const float* pw    = (const float*)d_in[2];   // [1024,64,64]
  const int*   tidx  = (const int*)d_in[3];     // [1024,64]
  const float* rough = (const float*)d_in[4];   // [1024,64]
  const float* W1    = (const float*)d_in[5];   // [1024,3136]
  const float* b1    = (const float*)d_in[6];   // [1024]
  const float* Wout  = (const float*)d_in[7];   // [1,1024]
  const float* bout  = (const float*)d_in[8];   // [1]
  float* out = (float*)d_out;                   // [1024,65]

  const int CHUNK = 16384;
  u16* A16    = (u16*)d_ws;                 // 1024*1024
  u16* allm16 = A16 + 1024 * 1024;          // 10240*1024 (rows>=10000 zero)
  u16* W1a    = allm16 + 10240 * 1024;      // 1024*1024
  u16* W1b    = W1a + 1024 * 1024;          // 1024*1024
  u16* W1cp   = W1b + 1024 * 1024;          // 1024*1088
  u16* Aproj  = W1cp + 1024 * 1088;         // 1024*1024 bf16
  u16* Bproj  = Aproj + 1024 * 1024;        // 10240*1024 bf16
  u16* Cmat   = Bproj + 10240 * 1024;       // CHUNK*1088 bf16

  size_t need = (size_t)2 * ((size_t)1024*1024 + 10240*1024 + 1024*1024 + 1024*1024
              + 1024*1088 + 1024*1024 + 10240*1024 + (size_t)CHUNK*1088);
  if (ws_size < need) {
    fprintf(stderr, "kernel_launch: ws_size %zu < needed %zu\n", ws_size, need);
    return;
  }

  // allow 128KiB dynamic LDS (deterministic, idempotent host-side call)
  hipFuncSetAttribute((const void*)&gemm256<false>,
                      hipFuncAttributeMaxDynamicSharedMemorySize, 131072);
  hipFuncSetAttribute((const void*)&gemm256<true>,
                      hipFuncAttributeMaxDynamicSharedMemorySize, 131072);

  // --- conversions / weight splits (bf16) ---
  {
    int t4;
    t4 = 1024 * 256;
    k_cvt<<<(t4 + 255) / 256, 256, 0, stream>>>(W1, 3136, 0,    1024, 256, t4, W1a, 1024, 0);
    k_cvt<<<(t4 + 255) / 256, 256, 0, stream>>>(W1, 3136, 1024, 1024, 256, t4, W1b, 1024, 0);
    k_cvt<<<(t4 + 255) / 256, 256, 0, stream>>>(W1, 3136, 2048, 1024, 256, t4, W1cp, 1088, 0);
    t4 = 1024 * 16;
    k_cvt<<<(t4 + 255) / 256, 256, 0, stream>>>(W1, 3136, 3072, 1024, 16, t4, W1cp, 1088, 1024);
    t4 = 1024 * 256;
    k_cvt<<<(t4 + 255) / 256, 256, 0, stream>>>(ments, 1024, 0, 1024, 256, t4, A16, 1024, 0);
    t4 = 10240 * 256;
    k_cvt<<<(t4 + 255) / 256, 256, 0, stream>>>(allm, 1024, 0, 10000, 256, t4, allm16, 1024, 0);
  }

  // --- projection GEMMs ---
  gemm128<<<dim3(8, 8), 256, 0, stream>>>(A16, 1024, W1a, 1024, 16, Aproj, 1024);
  gemm256<false><<<dim3(40, 4), 512, 131072, stream>>>(allm16, 1024, W1b, 1024, 16,
                                                       Bproj, 1024,
                                                       nullptr, nullptr, nullptr, nullptr,
                                                       nullptr, nullptr, 0);

  // --- init out with EPS column and rough+bout ---
  k_init<<<260, 256, 0, stream>>>(rough, bout, out);

  // --- chunked: build Cmat = [a*b | pw] bf16, then fused 256^2 GEMM+epilogue ---
  for (int c = 0; c < 4; ++c) {
    int r0 = c * CHUNK;
    k_build_cmat<<<(CHUNK * 272) / 256, 256, 0, stream>>>(ments, allm, pw, tidx, Cmat, r0);
    gemm256<true><<<dim3(CHUNK / 256, 4), 512, 131072, stream>>>(Cmat, 1088, W1cp, 1088, 17,
                                                                 nullptr, 0,
                                                                 Aproj, Bproj, b1, Wout,
                                                                 tidx, out, r0);
  }
}

// Round 4
// 394.616 us; speedup vs baseline: 1.3075x; 1.3075x over previous
//
#include <hip/hip_runtime.h>
#include <hip/hip_bf16.h>
#include <cstdint>
#include <cstdio>

typedef unsigned short u16;
typedef unsigned int   u32;
typedef __attribute__((ext_vector_type(8))) short bf16x8;   // 8 bf16 (4 VGPRs)
typedef __attribute__((ext_vector_type(4))) float f32x4;
typedef __attribute__((ext_vector_type(4))) u16   u16x4;

#define GLOBAL_AS __attribute__((address_space(1)))
#define LDS_AS    __attribute__((address_space(3)))

static __device__ __forceinline__ u16 f2bf(float f) {
  u32 u = __builtin_bit_cast(u32, f);
  u = (u + 0x7fffu + ((u >> 16) & 1u)) >> 16;   // RNE
  return (u16)u;
}
static __device__ __forceinline__ float bf2f(u16 v) {
  return __builtin_bit_cast(float, (u32)v << 16);
}
static __device__ __forceinline__ void gload_lds16(const void* g, void* l) {
  __builtin_amdgcn_global_load_lds((GLOBAL_AS u32*)g, (LDS_AS u32*)l, 16, 0, 0);
}

// ---------------------------------------------------------------------------
__global__ void k_cvt(const float* __restrict__ src, int ld, int c0,
                      int rows_src, int cols4, int total4,
                      u16* __restrict__ dst, int ldd, int dcol) {
  int gid = blockIdx.x * 256 + threadIdx.x;
  if (gid >= total4) return;
  int r = gid / cols4;
  int c = (gid - r * cols4) * 4;
  u16x4 o = {0, 0, 0, 0};
  if (r < rows_src) {
    const float4 v = *(const float4*)&src[(size_t)r * ld + c0 + c];
    o[0] = f2bf(v.x); o[1] = f2bf(v.y); o[2] = f2bf(v.z); o[3] = f2bf(v.w);
  }
  *(u16x4*)&dst[(size_t)r * ldd + dcol + c] = o;
}

// ---------------------------------------------------------------------------
__global__ void k_init(const float* __restrict__ rough,
                       const float* __restrict__ bout,
                       float* __restrict__ out) {
  int i = blockIdx.x * 256 + threadIdx.x;
  if (i >= 1024 * 65) return;
  int bi = i / 65, c = i - bi * 65;
  out[i] = (c == 0) ? 1e-7f : rough[bi * 64 + c - 1] + bout[0];
}

// ---------------------------------------------------------------------------
__global__ void k_build_cmat(const float* __restrict__ ments,
                             const float* __restrict__ allm,
                             const float* __restrict__ pw,
                             const int* __restrict__ topidx,
                             u16* __restrict__ Cmat, int r0) {
  int gid = blockIdx.x * 256 + threadIdx.x;   // 16384*272 exact
  int lr = gid / 272;
  int c4 = gid - lr * 272;
  int r  = r0 + lr;
  int bi = r >> 6;
  u16x4 o;
  if (c4 < 256) {
    int k   = c4 * 4;
    int idx = topidx[r];
    float4 a = *(const float4*)&ments[(size_t)bi * 1024 + k];
    float4 b = *(const float4*)&allm[(size_t)idx * 1024 + k];
    o[0] = f2bf(a.x * b.x); o[1] = f2bf(a.y * b.y);
    o[2] = f2bf(a.z * b.z); o[3] = f2bf(a.w * b.w);
  } else {
    int k = (c4 - 256) * 4;
    float4 p = *(const float4*)&pw[(size_t)r * 64 + k];
    o[0] = f2bf(p.x); o[1] = f2bf(p.y); o[2] = f2bf(p.z); o[3] = f2bf(p.w);
  }
  *(u16x4*)&Cmat[(size_t)lr * 1088 + c4 * 4] = o;
}

// ---------------------------------------------------------------------------
// gemm128: 128x128 2-phase kernel, used only for the tiny Aproj GEMM.
__global__ __launch_bounds__(256)
void gemm128(const u16* __restrict__ A, int lda,
             const u16* __restrict__ B, int ldb, int Ksteps,
             u16* __restrict__ C, int ldc) {
  __shared__ u16 As[128 * 64];
  __shared__ u16 Bs[128 * 64];
  const int t = threadIdx.x;
  const int w = t >> 6, l = t & 63;
  const int wr = w >> 1, wc = w & 1;
  const int brow = blockIdx.x * 128;
  const int bcol = blockIdx.y * 128;
  const int srow = t >> 3;
  const int scol = (t & 7) * 8;
  const int gsw  = (((t & 7) ^ ((t >> 3) & 7))) * 8;

  f32x4 acc[4][4] = {};
  for (int ks = 0; ks < Ksteps; ++ks) {
    const int kb = ks * 64;
#pragma unroll
    for (int q = 0; q < 4; ++q) {
      int r = q * 32 + srow;
      gload_lds16(A + (size_t)(brow + r) * lda + kb + gsw, &As[r * 64 + scol]);
      gload_lds16(B + (size_t)(bcol + r) * ldb + kb + gsw, &Bs[r * 64 + scol]);
    }
    __syncthreads();
#pragma unroll
    for (int kk = 0; kk < 2; ++kk) {
      bf16x8 af[4], bfr[4];
      const int pg = ((kk * 4 + (l >> 4)) ^ (l & 7)) * 8;
#pragma unroll
      for (int m = 0; m < 4; ++m)
        af[m] = *(const bf16x8*)&As[(wr * 64 + m * 16 + (l & 15)) * 64 + pg];
#pragma unroll
      for (int n = 0; n < 4; ++n)
        bfr[n] = *(const bf16x8*)&Bs[(wc * 64 + n * 16 + (l & 15)) * 64 + pg];
#pragma unroll
      for (int m = 0; m < 4; ++m)
#pragma unroll
        for (int n = 0; n < 4; ++n)
          acc[m][n] = __builtin_amdgcn_mfma_f32_16x16x32_bf16(af[m], bfr[n], acc[m][n], 0, 0, 0);
    }
    __syncthreads();
  }
#pragma unroll
  for (int m = 0; m < 4; ++m)
#pragma unroll
    for (int n = 0; n < 4; ++n)
#pragma unroll
      for (int reg = 0; reg < 4; ++reg) {
        int row = brow + wr * 64 + m * 16 + (l >> 4) * 4 + reg;
        int col = bcol + wc * 64 + n * 16 + (l & 15);
        C[(size_t)row * ldc + col] = f2bf(acc[m][n][reg]);
      }
}

// ---------------------------------------------------------------------------
// gemm256: 256x256, BK=64, 512 thr (8 waves 2Mx4N). m201-shaped phases:
//   [ds_reads; stage; s_barrier; lgkmcnt(0); sched_barrier(0);
//    setprio(1); 16 MFMA; setprio(0); counted vmcnt; s_barrier]
// Per tile t (4 phases, buf=t&1): B frags register-cached at q0 (8 reads);
// A halves bit5-interleaved so phase q reads only half q&1 (4 reads/phase).
// Stage: ALL 8 loads of tile t+1 at q0 (opposite buffer fully dead there).
// vmcnt ledger (per wave): q0 post-MFMA vmcnt(8) [drains Ah1(t), leaves 8
// of tile t+1]; last tile vmcnt(0). q3 post-MFMA vmcnt(2) [completes
// B(t+1)+Ah0(t+1), leaves Ah1(t+1)] -> 4-phase stage->use distance.
// Prologue: stageTile(0); vmcnt(2); barrier.
template<bool FUSED>
__global__ __launch_bounds__(512, 1)
void gemm256(const u16* __restrict__ A, int lda,
             const u16* __restrict__ B, int ldb, int NT,
             u16* __restrict__ C, int ldc,
             const u16* __restrict__ Aproj, const u16* __restrict__ Bproj,
             const float* __restrict__ b1, const float* __restrict__ Wout,
             const int* __restrict__ topidx, float* __restrict__ out, int r0) {
  extern __shared__ u16 lds[];
  u16* As = lds;                        // [2buf][2half][128][64] (A rows bit5-interleaved)
  u16* Bs = lds + 2 * 2 * 128 * 64;     // [2buf][256][64]

  const int t = threadIdx.x;
  const int l = t & 63;
  const int w = t >> 6;                 // 0..7
  const int wrow = w >> 2, wcol = w & 3;
  const int brow = blockIdx.x * 256;
  const int bcol = blockIdx.y * 256;

  const int sr  = t >> 3;               // 0..63
  const int sc  = (t & 7) * 8;          // linear LDS dest col
  const int gsw = ((t & 7) ^ (sr & 7)) * 8;  // pre-swizzled global col

  // stage order within a tile: Bh0(2), Bh1(2), Ah0(2), Ah1(2) = 8 loads.
  auto stageTile = [&](int kt) {
    const int cb = kt & 1;
#pragma unroll
    for (int s = 0; s < 4; ++s) {
      int lr = sr + 64 * s;             // B rows 0..255 in order
      gload_lds16(B + (size_t)(bcol + lr) * ldb + kt * 64 + gsw,
                  &Bs[(cb * 256 + lr) * 64 + sc]);
    }
#pragma unroll
    for (int h = 0; h < 2; ++h)
#pragma unroll
      for (int s = 0; s < 2; ++s) {
        int lr = sr + 64 * s;           // local row in half
        int g  = ((lr >> 5) << 6) + h * 32 + (lr & 31);   // bit5-interleave
        gload_lds16(A + (size_t)(brow + g) * lda + kt * 64 + gsw,
                    &As[((cb * 2 + h) * 128 + lr) * 64 + sc]);
      }
  };

  f32x4 acc[8][4] = {};

  // prologue
  stageTile(0);
  asm volatile("s_waitcnt vmcnt(2)" ::: "memory");   // B(0)+Ah0(0) done
  __builtin_amdgcn_s_barrier();

  for (int kt = 0; kt < NT; ++kt) {
    const int cbuf = kt & 1;
    const bool have_next = (kt + 1 < NT);
    bf16x8 bfr[4][2];                   // B frags, live all 4 phases
#pragma unroll
    for (int q = 0; q < 4; ++q) {
      // --- ds reads (before barrier: latency hidden under barrier wait) ---
      if (q == 0) {
#pragma unroll
        for (int n = 0; n < 4; ++n) {
          int row = wcol * 64 + n * 16 + (l & 15);
#pragma unroll
          for (int kk = 0; kk < 2; ++kk) {
            int gran = (kk * 4 + (l >> 4)) ^ (l & 7);
            bfr[n][kk] = *(const bf16x8*)&Bs[(cbuf * 256 + row) * 64 + gran * 8];
          }
        }
      }
      bf16x8 af[2][2];
#pragma unroll
      for (int m2 = 0; m2 < 2; ++m2) {
        int m = 2 * q + m2;
        int g = wrow * 128 + m * 16 + (l & 15);
        int lra = ((g >> 6) << 5) + (g & 31);
#pragma unroll
        for (int kk = 0; kk < 2; ++kk) {
          int gran = (kk * 4 + (l >> 4)) ^ (l & 7);
          af[m2][kk] = *(const bf16x8*)&As[((cbuf * 2 + (q & 1)) * 128 + lra) * 64 + gran * 8];
        }
      }

      // --- stage: full next tile at q0 ---
      if (q == 0 && have_next) stageTile(kt + 1);

      // --- barrier; wait own ds_reads; pin; MFMA ---
      __builtin_amdgcn_s_barrier();
      asm volatile("s_waitcnt lgkmcnt(0)" ::: "memory");
      __builtin_amdgcn_sched_barrier(0);
      __builtin_amdgcn_s_setprio(1);
#pragma unroll
      for (int m2 = 0; m2 < 2; ++m2)
#pragma unroll
        for (int n = 0; n < 4; ++n)
#pragma unroll
          for (int kk = 0; kk < 2; ++kk)
            acc[2 * q + m2][n] = __builtin_amdgcn_mfma_f32_16x16x32_bf16(
                af[m2][kk], bfr[n][kk], acc[2 * q + m2][n], 0, 0, 0);
      __builtin_amdgcn_s_setprio(0);

      // --- counted vmcnt, then closing barrier ---
      if (q == 0) {
        if (have_next) asm volatile("s_waitcnt vmcnt(8)" ::: "memory");  // Ah1(kt) ready
        else           asm volatile("s_waitcnt vmcnt(0)" ::: "memory");
      } else if (q == 3 && have_next) {
        asm volatile("s_waitcnt vmcnt(2)" ::: "memory");  // B(kt+1)+Ah0(kt+1) ready
      }
      __builtin_amdgcn_s_barrier();
    }
  }

  // --- epilogue ---
  if constexpr (FUSED) {
    float b1c[4], wo[4];
#pragma unroll
    for (int n = 0; n < 4; ++n) {
      int col = bcol + wcol * 64 + n * 16 + (l & 15);
      b1c[n] = b1[col];
      wo[n]  = Wout[col];
    }
#pragma unroll
    for (int m = 0; m < 8; ++m) {
#pragma unroll
      for (int reg = 0; reg < 4; ++reg) {
        int gr = r0 + brow + wrow * 128 + m * 16 + (l >> 4) * 4 + reg;
        int bi = gr >> 6;
        int mi = topidx[gr];
        float s = 0.f;
#pragma unroll
        for (int n = 0; n < 4; ++n) {
          int col = bcol + wcol * 64 + n * 16 + (l & 15);
          float v = acc[m][n][reg] + bf2f(Aproj[(size_t)bi * 1024 + col])
                  + bf2f(Bproj[(size_t)mi * 1024 + col]) + b1c[n];
          v = v > 0.f ? v : 0.01f * v;          // leaky_relu(0.01)
          s += v * wo[n];
        }
        s += __shfl_xor(s, 1);
        s += __shfl_xor(s, 2);
        s += __shfl_xor(s, 4);
        s += __shfl_xor(s, 8);
        if ((l & 15) == 0)
          atomicAdd(&out[bi * 65 + 1 + (gr & 63)], s);
      }
    }
  } else {
#pragma unroll
    for (int m = 0; m < 8; ++m)
#pragma unroll
      for (int n = 0; n < 4; ++n)
#pragma unroll
        for (int reg = 0; reg < 4; ++reg) {
          int row = brow + wrow * 128 + m * 16 + (l >> 4) * 4 + reg;
          int col = bcol + wcol * 64 + n * 16 + (l & 15);
          C[(size_t)row * ldc + col] = f2bf(acc[m][n][reg]);
        }
  }
}

// ---------------------------------------------------------------------------
extern "C" void kernel_launch(void* const* d_in, const int* in_sizes, int n_in,
                              void* d_out, int out_size, void* d_ws, size_t ws_size,
                              hipStream_t stream) {
  const float* allm  = (const float*)d_in[0];   // [10000,1024]
  const float* ments = (const float*)d_in[1];   // [1024,1024]
  const float* pw    = (const float*)d_in[2];   // [1024,64,64]
  const int*   tidx  = (const int*)d_in[3];     // [1024,64]
  const float* rough = (const float*)d_in[4];   // [1024,64]
  const float* W1    = (const float*)d_in[5];   // [1024,3136]
  const float* b1    = (const float*)d_in[6];   // [1024]
  const float* Wout  = (const float*)d_in[7];   // [1,1024]
  const float* bout  = (const float*)d_in[8];   // [1]
  float* out = (float*)d_out;                   // [1024,65]

  const int CHUNK = 16384;
  u16* A16    = (u16*)d_ws;                 // 1024*1024
  u16* allm16 = A16 + 1024 * 1024;          // 10240*1024 (rows>=10000 zero)
  u16* W1a    = allm16 + 10240 * 1024;      // 1024*1024
  u16* W1b    = W1a + 1024 * 1024;          // 1024*1024
  u16* W1cp   = W1b + 1024 * 1024;          // 1024*1088
  u16* Aproj  = W1cp + 1024 * 1088;         // 1024*1024 bf16
  u16* Bproj  = Aproj + 1024 * 1024;        // 10240*1024 bf16
  u16* Cmat   = Bproj + 10240 * 1024;       // CHUNK*1088 bf16

  size_t need = (size_t)2 * ((size_t)1024*1024 + 10240*1024 + 1024*1024 + 1024*1024
              + 1024*1088 + 1024*1024 + 10240*1024 + (size_t)CHUNK*1088);
  if (ws_size < need) {
    fprintf(stderr, "kernel_launch: ws_size %zu < needed %zu\n", ws_size, need);
    return;
  }

  hipFuncSetAttribute((const void*)&gemm256<false>,
                      hipFuncAttributeMaxDynamicSharedMemorySize, 131072);
  hipFuncSetAttribute((const void*)&gemm256<true>,
                      hipFuncAttributeMaxDynamicSharedMemorySize, 131072);

  // --- conversions / weight splits (bf16) ---
  {
    int t4;
    t4 = 1024 * 256;
    k_cvt<<<(t4 + 255) / 256, 256, 0, stream>>>(W1, 3136, 0,    1024, 256, t4, W1a, 1024, 0);
    k_cvt<<<(t4 + 255) / 256, 256, 0, stream>>>(W1, 3136, 1024, 1024, 256, t4, W1b, 1024, 0);
    k_cvt<<<(t4 + 255) / 256, 256, 0, stream>>>(W1, 3136, 2048, 1024, 256, t4, W1cp, 1088, 0);
    t4 = 1024 * 16;
    k_cvt<<<(t4 + 255) / 256, 256, 0, stream>>>(W1, 3136, 3072, 1024, 16, t4, W1cp, 1088, 1024);
    t4 = 1024 * 256;
    k_cvt<<<(t4 + 255) / 256, 256, 0, stream>>>(ments, 1024, 0, 1024, 256, t4, A16, 1024, 0);
    t4 = 10240 * 256;
    k_cvt<<<(t4 + 255) / 256, 256, 0, stream>>>(allm, 1024, 0, 10000, 256, t4, allm16, 1024, 0);
  }

  // --- projection GEMMs ---
  gemm128<<<dim3(8, 8), 256, 0, stream>>>(A16, 1024, W1a, 1024, 16, Aproj, 1024);
  gemm256<false><<<dim3(40, 4), 512, 131072, stream>>>(allm16, 1024, W1b, 1024, 16,
                                                       Bproj, 1024,
                                                       nullptr, nullptr, nullptr, nullptr,
                                                       nullptr, nullptr, 0);

  // --- init out with EPS column and rough+bout ---
  k_init<<<260, 256, 0, stream>>>(rough, bout, out);

  // --- chunked: build Cmat = [a*b | pw] bf16, then fused 256^2 GEMM+epilogue ---
  for (int c = 0; c < 4; ++c) {
    int r0 = c * CHUNK;
    k_build_cmat<<<(CHUNK * 272) / 256, 256, 0, stream>>>(ments, allm, pw, tidx, Cmat, r0);
    gemm256<true><<<dim3(CHUNK / 256, 4), 512, 131072, stream>>>(Cmat, 1088, W1cp, 1088, 17,
                                                                 nullptr, 0,
                                                                 Aproj, Bproj, b1, Wout,
                                                                 tidx, out, r0);
  }
}

// Round 5
// 319.469 us; speedup vs baseline: 1.6151x; 1.2352x over previous
//
#include <hip/hip_runtime.h>
#include <hip/hip_bf16.h>
#include <cstdint>
#include <cstdio>

typedef unsigned short u16;
typedef unsigned int   u32;
typedef __attribute__((ext_vector_type(8))) short bf16x8;   // 8 bf16 (4 VGPRs)
typedef __attribute__((ext_vector_type(4))) float f32x4;
typedef __attribute__((ext_vector_type(4))) u16   u16x4;
typedef __attribute__((ext_vector_type(8))) u16   u16x8;

#define GLOBAL_AS __attribute__((address_space(1)))
#define LDS_AS    __attribute__((address_space(3)))

static __device__ __forceinline__ u16 f2bf(float f) {
  u32 u = __builtin_bit_cast(u32, f);
  u = (u + 0x7fffu + ((u >> 16) & 1u)) >> 16;   // RNE
  return (u16)u;
}
static __device__ __forceinline__ float bf2f(u16 v) {
  return __builtin_bit_cast(float, (u32)v << 16);
}
static __device__ __forceinline__ void gload_lds16(const void* g, void* l) {
  __builtin_amdgcn_global_load_lds((GLOBAL_AS u32*)g, (LDS_AS u32*)l, 16, 0, 0);
}

// ---------------------------------------------------------------------------
__global__ void k_cvt(const float* __restrict__ src, int ld, int c0,
                      int rows_src, int cols4, int total4,
                      u16* __restrict__ dst, int ldd, int dcol) {
  int gid = blockIdx.x * 256 + threadIdx.x;
  if (gid >= total4) return;
  int r = gid / cols4;
  int c = (gid - r * cols4) * 4;
  u16x4 o = {0, 0, 0, 0};
  if (r < rows_src) {
    const float4 v = *(const float4*)&src[(size_t)r * ld + c0 + c];
    o[0] = f2bf(v.x); o[1] = f2bf(v.y); o[2] = f2bf(v.z); o[3] = f2bf(v.w);
  }
  *(u16x4*)&dst[(size_t)r * ldd + dcol + c] = o;
}

// ---------------------------------------------------------------------------
__global__ void k_init(const float* __restrict__ rough,
                       const float* __restrict__ bout,
                       float* __restrict__ out) {
  int i = blockIdx.x * 256 + threadIdx.x;
  if (i >= 1024 * 65) return;
  int bi = i / 65, c = i - bi * 65;
  out[i] = (c == 0) ? 1e-7f : rough[bi * 64 + c - 1] + bout[0];
}

// ---------------------------------------------------------------------------
// k_build_cmat: bf16 sources, 8 elems/thread. 136 = 1088/8 groups per row.
__global__ void k_build_cmat(const u16* __restrict__ A16,
                             const u16* __restrict__ allm16,
                             const float* __restrict__ pw,
                             const int* __restrict__ topidx,
                             u16* __restrict__ Cmat, int r0) {
  int gid = blockIdx.x * 256 + threadIdx.x;   // 16384*136 exact
  int lr = gid / 136;
  int c8 = gid - lr * 136;
  int r  = r0 + lr;
  u16x8 o;
  if (c8 < 128) {
    int k   = c8 * 8;
    int idx = topidx[r];
    int bi  = r >> 6;
    u16x8 a = *(const u16x8*)&A16[(size_t)bi * 1024 + k];
    u16x8 b = *(const u16x8*)&allm16[(size_t)idx * 1024 + k];
#pragma unroll
    for (int j = 0; j < 8; ++j) o[j] = f2bf(bf2f(a[j]) * bf2f(b[j]));
  } else {
    int k = (c8 - 128) * 8;
    float4 p0 = *(const float4*)&pw[(size_t)r * 64 + k];
    float4 p1 = *(const float4*)&pw[(size_t)r * 64 + k + 4];
    o[0] = f2bf(p0.x); o[1] = f2bf(p0.y); o[2] = f2bf(p0.z); o[3] = f2bf(p0.w);
    o[4] = f2bf(p1.x); o[5] = f2bf(p1.y); o[6] = f2bf(p1.z); o[7] = f2bf(p1.w);
  }
  *(u16x8*)&Cmat[(size_t)lr * 1088 + c8 * 8] = o;
}

// ---------------------------------------------------------------------------
// gemm128: 128x128 2-phase kernel, used only for the tiny Aproj GEMM.
// bias (b1) folded into the bf16 output.
__global__ __launch_bounds__(256)
void gemm128(const u16* __restrict__ A, int lda,
             const u16* __restrict__ B, int ldb, int Ksteps,
             u16* __restrict__ C, int ldc, const float* __restrict__ bias) {
  __shared__ u16 As[128 * 64];
  __shared__ u16 Bs[128 * 64];
  const int t = threadIdx.x;
  const int w = t >> 6, l = t & 63;
  const int wr = w >> 1, wc = w & 1;
  const int brow = blockIdx.x * 128;
  const int bcol = blockIdx.y * 128;
  const int srow = t >> 3;
  const int scol = (t & 7) * 8;
  const int gsw  = (((t & 7) ^ ((t >> 3) & 7))) * 8;

  f32x4 acc[4][4] = {};
  for (int ks = 0; ks < Ksteps; ++ks) {
    const int kb = ks * 64;
#pragma unroll
    for (int q = 0; q < 4; ++q) {
      int r = q * 32 + srow;
      gload_lds16(A + (size_t)(brow + r) * lda + kb + gsw, &As[r * 64 + scol]);
      gload_lds16(B + (size_t)(bcol + r) * ldb + kb + gsw, &Bs[r * 64 + scol]);
    }
    __syncthreads();
#pragma unroll
    for (int kk = 0; kk < 2; ++kk) {
      bf16x8 af[4], bfr[4];
      const int pg = ((kk * 4 + (l >> 4)) ^ (l & 7)) * 8;
#pragma unroll
      for (int m = 0; m < 4; ++m)
        af[m] = *(const bf16x8*)&As[(wr * 64 + m * 16 + (l & 15)) * 64 + pg];
#pragma unroll
      for (int n = 0; n < 4; ++n)
        bfr[n] = *(const bf16x8*)&Bs[(wc * 64 + n * 16 + (l & 15)) * 64 + pg];
#pragma unroll
      for (int m = 0; m < 4; ++m)
#pragma unroll
        for (int n = 0; n < 4; ++n)
          acc[m][n] = __builtin_amdgcn_mfma_f32_16x16x32_bf16(af[m], bfr[n], acc[m][n], 0, 0, 0);
    }
    __syncthreads();
  }
#pragma unroll
  for (int m = 0; m < 4; ++m)
#pragma unroll
    for (int n = 0; n < 4; ++n)
#pragma unroll
      for (int reg = 0; reg < 4; ++reg) {
        int row = brow + wr * 64 + m * 16 + (l >> 4) * 4 + reg;
        int col = bcol + wc * 64 + n * 16 + (l & 15);
        float v = acc[m][n][reg] + (bias ? bias[col] : 0.f);
        C[(size_t)row * ldc + col] = f2bf(v);
      }
}

// ---------------------------------------------------------------------------
// gemm256: 256x256, BK=64, 512 thr (8 waves 2Mx4N). m201-faithful schedule:
// per phase: [ds_reads; stage ONE half-tile (2 gloads); (q0: lgkmcnt(8));
//   s_barrier; lgkmcnt(0); sched_barrier(0); setprio(1); 16 MFMA; setprio(0);
//   counted vmcnt (q0/q3 only); s_barrier]
// Stage placement (region-deadness exact): q0->Ah0(t+1), q1->Ah1(t+1),
//   q2->Bh0(t+2), q3->Bh1(t+2). B frags register-cached at q0; A halves
//   bit5-interleaved so phase q reads only half q&1.
// Ledger: q0-post vmcnt(6) guards Ah1(t) [3-ph distance]; q3-post vmcnt(6)
//   guards B(t+1)+Ah0(t+1) [3-ph]. Tail: q0-post vmcnt(0) when no t+1;
//   q3-post vmcnt(2) when no t+2. Prologue: Bh0(0),Bh1(0),Ah0(0),Ah1(0),
//   Bh0(1),Bh1(1); vmcnt(6); barrier.
// FUSED epilogue: Bproj 256x256 slice staged into LDS (reused) via
//   gload_lds, Aproj(+b1) hoisted to 8 loads/thread, leaky_relu, *Wout,
//   16-lane shfl reduce, atomicAdd.
template<bool FUSED>
__global__ __launch_bounds__(512, 1)
void gemm256(const u16* __restrict__ A, int lda,
             const u16* __restrict__ B, int ldb, int NT,
             u16* __restrict__ C, int ldc,
             const u16* __restrict__ Aproj, const u16* __restrict__ Bproj,
             const float* __restrict__ Wout,
             const int* __restrict__ topidx, float* __restrict__ out, int r0) {
  extern __shared__ u16 lds[];
  u16* As = lds;                        // [2buf][2half][128][64], rows bit5-interleaved
  u16* Bs = lds + 2 * 2 * 128 * 64;     // [2buf][256][64]

  const int t = threadIdx.x;
  const int l = t & 63;
  const int w = t >> 6;                 // 0..7
  const int wrow = w >> 2, wcol = w & 3;
  const int brow = blockIdx.x * 256;
  const int bcol = blockIdx.y * 256;

  const int sr  = t >> 3;               // 0..63
  const int sc  = (t & 7) * 8;          // linear LDS dest col
  const int gsw = ((t & 7) ^ (sr & 7)) * 8;  // pre-swizzled global col

  auto stageA = [&](int kt, int h) {    // one A half-tile: 2 loads
    if (kt >= NT) return;
#pragma unroll
    for (int s = 0; s < 2; ++s) {
      int lr = sr + 64 * s;
      int g  = ((lr >> 5) << 6) + h * 32 + (lr & 31);   // bit5-interleave
      gload_lds16(A + (size_t)(brow + g) * lda + kt * 64 + gsw,
                  &As[(((kt & 1) * 2 + h) * 128 + lr) * 64 + sc]);
    }
  };
  auto stageB = [&](int kt, int h) {    // one B half-tile: 2 loads
    if (kt >= NT) return;
#pragma unroll
    for (int s = 0; s < 2; ++s) {
      int lr = h * 128 + sr + 64 * s;
      gload_lds16(B + (size_t)(bcol + lr) * ldb + kt * 64 + gsw,
                  &Bs[((kt & 1) * 256 + lr) * 64 + sc]);
    }
  };

  f32x4 acc[8][4] = {};

  // prologue: steady-state issue order
  stageB(0, 0); stageB(0, 1); stageA(0, 0); stageA(0, 1);
  stageB(1, 0); stageB(1, 1);
  asm volatile("s_waitcnt vmcnt(6)" ::: "memory");   // B(0)+Ah0(0) landed
  __builtin_amdgcn_s_barrier();

  for (int kt = 0; kt < NT; ++kt) {
    const int cbuf = kt & 1;
    bf16x8 bfr[4][2];                   // B frags, live all 4 phases
#pragma unroll
    for (int q = 0; q < 4; ++q) {
      // --- ds reads (pre-barrier) ---
      if (q == 0) {
#pragma unroll
        for (int n = 0; n < 4; ++n) {
          int row = wcol * 64 + n * 16 + (l & 15);
#pragma unroll
          for (int kk = 0; kk < 2; ++kk) {
            int gran = (kk * 4 + (l >> 4)) ^ (l & 7);
            bfr[n][kk] = *(const bf16x8*)&Bs[(cbuf * 256 + row) * 64 + gran * 8];
          }
        }
      }
      bf16x8 af[2][2];
#pragma unroll
      for (int m2 = 0; m2 < 2; ++m2) {
        int m = 2 * q + m2;
        int g = wrow * 128 + m * 16 + (l & 15);
        int lra = ((g >> 6) << 5) + (g & 31);
#pragma unroll
        for (int kk = 0; kk < 2; ++kk) {
          int gran = (kk * 4 + (l >> 4)) ^ (l & 7);
          af[m2][kk] = *(const bf16x8*)&As[((cbuf * 2 + (q & 1)) * 128 + lra) * 64 + gran * 8];
        }
      }

      // --- stage exactly one half-tile ---
      if      (q == 0) stageA(kt + 1, 0);
      else if (q == 1) stageA(kt + 1, 1);
      else if (q == 2) stageB(kt + 2, 0);
      else             stageB(kt + 2, 1);

      if (q == 0) asm volatile("s_waitcnt lgkmcnt(8)" ::: "memory");
      __builtin_amdgcn_s_barrier();
      asm volatile("s_waitcnt lgkmcnt(0)" ::: "memory");
      __builtin_amdgcn_sched_barrier(0);
      __builtin_amdgcn_s_setprio(1);
#pragma unroll
      for (int m2 = 0; m2 < 2; ++m2)
#pragma unroll
        for (int n = 0; n < 4; ++n)
#pragma unroll
          for (int kk = 0; kk < 2; ++kk)
            acc[2 * q + m2][n] = __builtin_amdgcn_mfma_f32_16x16x32_bf16(
                af[m2][kk], bfr[n][kk], acc[2 * q + m2][n], 0, 0, 0);
      __builtin_amdgcn_s_setprio(0);

      // --- counted waits (q0/q3 only), then closing barrier ---
      if (q == 0) {
        if (kt + 1 < NT) asm volatile("s_waitcnt vmcnt(6)" ::: "memory");
        else             asm volatile("s_waitcnt vmcnt(0)" ::: "memory");
      } else if (q == 3 && kt + 1 < NT) {
        if (kt + 2 < NT) asm volatile("s_waitcnt vmcnt(6)" ::: "memory");
        else             asm volatile("s_waitcnt vmcnt(2)" ::: "memory");
      }
      __builtin_amdgcn_s_barrier();
    }
  }

  // --- epilogue ---
  if constexpr (FUSED) {
    // stage Bproj[topidx[row]][bcol..bcol+256) into Pb[256][256] (reuses LDS)
    __syncthreads();
    u16* Pb = lds;
#pragma unroll
    for (int pass = 0; pass < 16; ++pass) {
      int rr = pass * 16 + (t >> 5);                  // lanes 0-31 -> rr0, 32-63 -> rr0+1
      int mi = topidx[r0 + brow + rr];
      int cc = (t & 31) * 8;                          // 16B per lane
      gload_lds16(&Bproj[(size_t)mi * 1024 + bcol + cc], &Pb[rr * 256 + cc]);
    }
    asm volatile("s_waitcnt vmcnt(0)" ::: "memory");
    __syncthreads();

    float wo[4], av[2][4];
    const int bi0 = ((r0 + brow) >> 6) + wrow * 2;
#pragma unroll
    for (int n = 0; n < 4; ++n) {
      int col = bcol + wcol * 64 + n * 16 + (l & 15);
      wo[n] = Wout[col];
#pragma unroll
      for (int j = 0; j < 2; ++j)
        av[j][n] = bf2f(Aproj[(size_t)(bi0 + j) * 1024 + col]);   // b1 pre-folded
    }
#pragma unroll
    for (int m = 0; m < 8; ++m) {
#pragma unroll
      for (int reg = 0; reg < 4; ++reg) {
        int lrow = wrow * 128 + m * 16 + (l >> 4) * 4 + reg;
        int gr = r0 + brow + lrow;
        float s = 0.f;
#pragma unroll
        for (int n = 0; n < 4; ++n) {
          int lcol = wcol * 64 + n * 16 + (l & 15);
          float v = acc[m][n][reg] + av[m >> 2][n] + bf2f(Pb[lrow * 256 + lcol]);
          v = v > 0.f ? v : 0.01f * v;          // leaky_relu(0.01)
          s += v * wo[n];
        }
        s += __shfl_xor(s, 1);
        s += __shfl_xor(s, 2);
        s += __shfl_xor(s, 4);
        s += __shfl_xor(s, 8);
        if ((l & 15) == 0)
          atomicAdd(&out[(gr >> 6) * 65 + 1 + (gr & 63)], s);
      }
    }
  } else {
#pragma unroll
    for (int m = 0; m < 8; ++m)
#pragma unroll
      for (int n = 0; n < 4; ++n)
#pragma unroll
        for (int reg = 0; reg < 4; ++reg) {
          int row = brow + wrow * 128 + m * 16 + (l >> 4) * 4 + reg;
          int col = bcol + wcol * 64 + n * 16 + (l & 15);
          C[(size_t)row * ldc + col] = f2bf(acc[m][n][reg]);
        }
  }
}

// ---------------------------------------------------------------------------
extern "C" void kernel_launch(void* const* d_in, const int* in_sizes, int n_in,
                              void* d_out, int out_size, void* d_ws, size_t ws_size,
                              hipStream_t stream) {
  const float* allm  = (const float*)d_in[0];   // [10000,1024]
  const float* ments = (const float*)d_in[1];   // [1024,1024]
  const float* pw    = (const float*)d_in[2];   // [1024,64,64]
  const int*   tidx  = (const int*)d_in[3];     // [1024,64]
  const float* rough = (const float*)d_in[4];   // [1024,64]
  const float* W1    = (const float*)d_in[5];   // [1024,3136]
  const float* b1    = (const float*)d_in[6];   // [1024]
  const float* Wout  = (const float*)d_in[7];   // [1,1024]
  const float* bout  = (const float*)d_in[8];   // [1]
  float* out = (float*)d_out;                   // [1024,65]

  const int CHUNK = 16384;
  u16* A16    = (u16*)d_ws;                 // 1024*1024
  u16* allm16 = A16 + 1024 * 1024;          // 10240*1024 (rows>=10000 zero)
  u16* W1a    = allm16 + 10240 * 1024;      // 1024*1024
  u16* W1b    = W1a + 1024 * 1024;          // 1024*1024
  u16* W1cp   = W1b + 1024 * 1024;          // 1024*1088
  u16* Aproj  = W1cp + 1024 * 1088;         // 1024*1024 bf16 (holds Aproj+b1)
  u16* Bproj  = Aproj + 1024 * 1024;        // 10240*1024 bf16
  u16* Cmat   = Bproj + 10240 * 1024;       // CHUNK*1088 bf16

  size_t need = (size_t)2 * ((size_t)1024*1024 + 10240*1024 + 1024*1024 + 1024*1024
              + 1024*1088 + 1024*1024 + 10240*1024 + (size_t)CHUNK*1088);
  if (ws_size < need) {
    fprintf(stderr, "kernel_launch: ws_size %zu < needed %zu\n", ws_size, need);
    return;
  }

  hipFuncSetAttribute((const void*)&gemm256<false>,
                      hipFuncAttributeMaxDynamicSharedMemorySize, 131072);
  hipFuncSetAttribute((const void*)&gemm256<true>,
                      hipFuncAttributeMaxDynamicSharedMemorySize, 131072);

  // --- conversions / weight splits (bf16) ---
  {
    int t4;
    t4 = 1024 * 256;
    k_cvt<<<(t4 + 255) / 256, 256, 0, stream>>>(W1, 3136, 0,    1024, 256, t4, W1a, 1024, 0);
    k_cvt<<<(t4 + 255) / 256, 256, 0, stream>>>(W1, 3136, 1024, 1024, 256, t4, W1b, 1024, 0);
    k_cvt<<<(t4 + 255) / 256, 256, 0, stream>>>(W1, 3136, 2048, 1024, 256, t4, W1cp, 1088, 0);
    t4 = 1024 * 16;
    k_cvt<<<(t4 + 255) / 256, 256, 0, stream>>>(W1, 3136, 3072, 1024, 16, t4, W1cp, 1088, 1024);
    t4 = 1024 * 256;
    k_cvt<<<(t4 + 255) / 256, 256, 0, stream>>>(ments, 1024, 0, 1024, 256, t4, A16, 1024, 0);
    t4 = 10240 * 256;
    k_cvt<<<(t4 + 255) / 256, 256, 0, stream>>>(allm, 1024, 0, 10000, 256, t4, allm16, 1024, 0);
  }

  // --- projection GEMMs (Aproj gets +b1 folded) ---
  gemm128<<<dim3(8, 8), 256, 0, stream>>>(A16, 1024, W1a, 1024, 16, Aproj, 1024, b1);
  gemm256<false><<<dim3(40, 4), 512, 131072, stream>>>(allm16, 1024, W1b, 1024, 16,
                                                       Bproj, 1024,
                                                       nullptr, nullptr, nullptr,
                                                       nullptr, nullptr, 0);

  // --- init out with EPS column and rough+bout ---
  k_init<<<260, 256, 0, stream>>>(rough, bout, out);

  // --- chunked: build Cmat = [a*b | pw] bf16, then fused 256^2 GEMM+epilogue ---
  for (int c = 0; c < 4; ++c) {
    int r0 = c * CHUNK;
    k_build_cmat<<<(CHUNK * 136) / 256, 256, 0, stream>>>(A16, allm16, pw, tidx, Cmat, r0);
    gemm256<true><<<dim3(CHUNK / 256, 4), 512, 131072, stream>>>(Cmat, 1088, W1cp, 1088, 17,
                                                                 nullptr, 0,
                                                                 Aproj, Bproj, Wout,
                                                                 tidx, out, r0);
  }
}